// Round 1
// baseline (954.487 us; speedup 1.0000x reference)
//
#include <hip/hip_runtime.h>

namespace {
constexpr int nB = 128;
constexpr int nS = 300;
constexpr int nC = 64;
constexpr int nH = 768;
constexpr int nM = 300;

constexpr int ST  = 64;                    // s tile
constexpr int NST = (nS + ST - 1) / ST;    // 5
constexpr int SP  = NST * ST;              // 320 (padded S)
constexpr int MT  = 32;                    // m tile (kernel B)
constexpr int NMT = (nM + MT - 1) / MT;    // 10
constexpr int KT  = 32;                    // k (H) tile
}

// ---------------------------------------------------------------------------
// Kernel A: G[b,s,c] = sum_h ctx[b,s,h] * resp[b,c,h]
// grid = nB * NST blocks, 256 threads. Each block: 64(s) x 64(c) tile, K=768.
// ---------------------------------------------------------------------------
__global__ __launch_bounds__(256) void kern_g(const float* __restrict__ ctx,
                                              const float* __restrict__ resp,
                                              float* __restrict__ G) {
    const int b   = blockIdx.x / NST;
    const int s0  = (blockIdx.x % NST) * ST;
    const int tid = threadIdx.x;

    __shared__ float As[ST][KT + 1];   // ctx tile  [s][k]
    __shared__ float Bs[nC][KT + 1];   // resp tile [c][k]

    const float* __restrict__ ctxb  = ctx  + (size_t)b * nS * nH;
    const float* __restrict__ respb = resp + (size_t)b * nC * nH;

    const int ts = (tid / 16) * 4;   // s row group
    const int tc = (tid % 16) * 4;   // c col group
    float acc[4][4] = {};

    for (int k0 = 0; k0 < nH; k0 += KT) {
        __syncthreads();
        for (int f = tid; f < ST * (KT / 4); f += 256) {   // 512 float4
            const int r  = f / (KT / 4);
            const int kq = (f % (KT / 4)) * 4;
            const int s  = s0 + r;
            float4 v = make_float4(0.f, 0.f, 0.f, 0.f);
            if (s < nS) v = *reinterpret_cast<const float4*>(ctxb + (size_t)s * nH + k0 + kq);
            As[r][kq + 0] = v.x; As[r][kq + 1] = v.y; As[r][kq + 2] = v.z; As[r][kq + 3] = v.w;
        }
        for (int f = tid; f < nC * (KT / 4); f += 256) {   // 512 float4
            const int r  = f / (KT / 4);
            const int kq = (f % (KT / 4)) * 4;
            float4 v = *reinterpret_cast<const float4*>(respb + (size_t)r * nH + k0 + kq);
            Bs[r][kq + 0] = v.x; Bs[r][kq + 1] = v.y; Bs[r][kq + 2] = v.z; Bs[r][kq + 3] = v.w;
        }
        __syncthreads();
        #pragma unroll
        for (int k = 0; k < KT; ++k) {
            const float a0 = As[ts + 0][k], a1 = As[ts + 1][k];
            const float a2 = As[ts + 2][k], a3 = As[ts + 3][k];
            const float c0 = Bs[tc + 0][k], c1 = Bs[tc + 1][k];
            const float c2 = Bs[tc + 2][k], c3 = Bs[tc + 3][k];
            acc[0][0] += a0 * c0; acc[0][1] += a0 * c1; acc[0][2] += a0 * c2; acc[0][3] += a0 * c3;
            acc[1][0] += a1 * c0; acc[1][1] += a1 * c1; acc[1][2] += a1 * c2; acc[1][3] += a1 * c3;
            acc[2][0] += a2 * c0; acc[2][1] += a2 * c1; acc[2][2] += a2 * c2; acc[2][3] += a2 * c3;
            acc[3][0] += a3 * c0; acc[3][1] += a3 * c1; acc[3][2] += a3 * c2; acc[3][3] += a3 * c3;
        }
    }
    #pragma unroll
    for (int i = 0; i < 4; ++i) {
        const int s = s0 + ts + i;
        if (s < nS) {
            float4 v = make_float4(acc[i][0], acc[i][1], acc[i][2], acc[i][3]);
            *reinterpret_cast<float4*>(G + ((size_t)b * nS + s) * nC + tc) = v;
        }
    }
}

// ---------------------------------------------------------------------------
// Kernel B: per (b, m-tile of 32):
//   W[m,s] = pos[m]·ctx[b,s]  (masked)  -> softmax over s -> P
//   w2[b,m,c] = sum_s P[m,s] * G[b,s,c]
// grid = nB * NMT blocks, 256 threads.
// ---------------------------------------------------------------------------
__global__ __launch_bounds__(256) void kern_b(const float* __restrict__ ctx,
                                              const float* __restrict__ pos,
                                              const int*  __restrict__ mask,
                                              const float* __restrict__ G,
                                              float* __restrict__ w2) {
    const int b   = blockIdx.x / NMT;
    const int m0  = (blockIdx.x % NMT) * MT;
    const int tid = threadIdx.x;

    __shared__ float Wrow[MT][SP + 1];    // logits, then unnormalized exp
    __shared__ float maskS[SP];
    __shared__ float rowScale[MT];
    __shared__ alignas(16) union Shm {
        struct { float pos[MT][KT + 1]; float ctxt[ST][KT + 1]; } p1;
        float gt[ST][nC + 4];
    } shm;

    const float* __restrict__ ctxb = ctx + (size_t)b * nS * nH;

    for (int s = tid; s < SP; s += 256)
        maskS[s] = (s < nS) ? (float)mask[b * nS + s] : 0.f;
    // (first use of maskS is after many __syncthreads below)

    const int pm = (tid % 16) * 2;   // m rows pm, pm+1
    const int ps = (tid / 16) * 4;   // s cols ps..ps+3

    // ---- phase 1: masked logits ----
    for (int st = 0; st < NST; ++st) {
        const int s0 = st * ST;
        float acc0[4] = {0.f, 0.f, 0.f, 0.f};
        float acc1[4] = {0.f, 0.f, 0.f, 0.f};
        for (int k0 = 0; k0 < nH; k0 += KT) {
            __syncthreads();
            {   // stage pos tile 32x32: 256 float4, one per thread
                const int r  = tid / (KT / 4);
                const int kq = (tid % (KT / 4)) * 4;
                const int m  = m0 + r;
                float4 v = make_float4(0.f, 0.f, 0.f, 0.f);
                if (m < nM) v = *reinterpret_cast<const float4*>(pos + (size_t)m * nH + k0 + kq);
                shm.p1.pos[r][kq + 0] = v.x; shm.p1.pos[r][kq + 1] = v.y;
                shm.p1.pos[r][kq + 2] = v.z; shm.p1.pos[r][kq + 3] = v.w;
            }
            for (int f = tid; f < ST * (KT / 4); f += 256) {   // ctx tile 64x32
                const int r  = f / (KT / 4);
                const int kq = (f % (KT / 4)) * 4;
                const int s  = s0 + r;
                float4 v = make_float4(0.f, 0.f, 0.f, 0.f);
                if (s < nS) v = *reinterpret_cast<const float4*>(ctxb + (size_t)s * nH + k0 + kq);
                shm.p1.ctxt[r][kq + 0] = v.x; shm.p1.ctxt[r][kq + 1] = v.y;
                shm.p1.ctxt[r][kq + 2] = v.z; shm.p1.ctxt[r][kq + 3] = v.w;
            }
            __syncthreads();
            #pragma unroll
            for (int k = 0; k < KT; ++k) {
                const float a0 = shm.p1.pos[pm + 0][k];
                const float a1 = shm.p1.pos[pm + 1][k];
                const float c0 = shm.p1.ctxt[ps + 0][k];
                const float c1 = shm.p1.ctxt[ps + 1][k];
                const float c2 = shm.p1.ctxt[ps + 2][k];
                const float c3 = shm.p1.ctxt[ps + 3][k];
                acc0[0] += a0 * c0; acc0[1] += a0 * c1; acc0[2] += a0 * c2; acc0[3] += a0 * c3;
                acc1[0] += a1 * c0; acc1[1] += a1 * c1; acc1[2] += a1 * c2; acc1[3] += a1 * c3;
            }
        }
        #pragma unroll
        for (int j = 0; j < 4; ++j) {
            const int s = s0 + ps + j;
            if (s < nS) {
                const float mv = maskS[s];
                Wrow[pm + 0][s] = acc0[j] * mv;
                Wrow[pm + 1][s] = acc1[j] * mv;
            } else {
                Wrow[pm + 0][s] = -1e30f;
                Wrow[pm + 1][s] = -1e30f;
            }
        }
    }
    __syncthreads();

    // ---- phase 2: softmax (store unnormalized exp, fold 1/sum later) ----
    {
        const int row = tid / 8;   // 0..31
        const int l8  = tid % 8;
        float mx = -1e30f;
        for (int s = l8; s < SP; s += 8) mx = fmaxf(mx, Wrow[row][s]);
        #pragma unroll
        for (int o = 4; o; o >>= 1) mx = fmaxf(mx, __shfl_xor(mx, o, 8));
        float sum = 0.f;
        for (int s = l8; s < SP; s += 8) {
            const float e = __expf(Wrow[row][s] - mx);
            Wrow[row][s] = e;
            sum += e;
        }
        #pragma unroll
        for (int o = 4; o; o >>= 1) sum += __shfl_xor(sum, o, 8);
        if (l8 == 0) rowScale[row] = 1.f / sum;
    }
    __syncthreads();

    // ---- phase 3: w2[m,c] = (1/sum_m) * sum_s e[m,s] * G[b,s,c] ----
    const int tm = (tid / 16) * 2;
    const int c0 = (tid % 16) * 4;
    float w0[4] = {0.f, 0.f, 0.f, 0.f};
    float w1[4] = {0.f, 0.f, 0.f, 0.f};
    for (int st = 0; st < NST; ++st) {
        __syncthreads();
        for (int f = tid; f < ST * (nC / 4); f += 256) {   // 1024 float4
            const int ss = f / (nC / 4);
            const int cq = (f % (nC / 4)) * 4;
            const int s  = st * ST + ss;
            float4 v = make_float4(0.f, 0.f, 0.f, 0.f);
            if (s < nS) v = *reinterpret_cast<const float4*>(G + ((size_t)b * nS + s) * nC + cq);
            *reinterpret_cast<float4*>(&shm.gt[ss][cq]) = v;
        }
        __syncthreads();
        #pragma unroll 8
        for (int ss = 0; ss < ST; ++ss) {
            const float p0 = Wrow[tm + 0][st * ST + ss];
            const float p1 = Wrow[tm + 1][st * ST + ss];
            const float4 g = *reinterpret_cast<const float4*>(&shm.gt[ss][c0]);
            w0[0] += p0 * g.x; w0[1] += p0 * g.y; w0[2] += p0 * g.z; w0[3] += p0 * g.w;
            w1[0] += p1 * g.x; w1[1] += p1 * g.y; w1[2] += p1 * g.z; w1[3] += p1 * g.w;
        }
    }
    const float r0 = rowScale[tm + 0];
    const float r1 = rowScale[tm + 1];
    const int mA = m0 + tm, mB = m0 + tm + 1;
    if (mA < nM) {
        float4 v = make_float4(w0[0] * r0, w0[1] * r0, w0[2] * r0, w0[3] * r0);
        *reinterpret_cast<float4*>(w2 + ((size_t)b * nM + mA) * nC + c0) = v;
    }
    if (mB < nM) {
        float4 v = make_float4(w1[0] * r1, w1[1] * r1, w1[2] * r1, w1[3] * r1);
        *reinterpret_cast<float4*>(w2 + ((size_t)b * nM + mB) * nC + c0) = v;
    }
}

// ---------------------------------------------------------------------------
// Kernel C: dot[b,c] = sum_m w2[b,m,c]^2
// ---------------------------------------------------------------------------
__global__ __launch_bounds__(256) void kern_c(const float* __restrict__ w2,
                                              float* __restrict__ out) {
    const int b = blockIdx.x;
    const int c = threadIdx.x % nC;
    const int g = threadIdx.x / nC;   // 0..3
    float s = 0.f;
    for (int m = g; m < nM; m += 4) {
        const float v = w2[((size_t)b * nM + m) * nC + c];
        s += v * v;
    }
    __shared__ float red[4][nC];
    red[g][c] = s;
    __syncthreads();
    if (g == 0) out[(size_t)b * nC + c] = red[0][c] + red[1][c] + red[2][c] + red[3][c];
}

extern "C" void kernel_launch(void* const* d_in, const int* in_sizes, int n_in,
                              void* d_out, int out_size, void* d_ws, size_t ws_size,
                              hipStream_t stream) {
    const float* ctx  = (const float*)d_in[0];   // [B,S,H]
    const float* resp = (const float*)d_in[1];   // [B,C,H]
    const float* pos  = (const float*)d_in[2];   // [M,H]
    const int*   mask = (const int*)d_in[3];     // [B,S]
    float* out = (float*)d_out;                  // [B,C]

    float* Gbuf  = (float*)d_ws;                           // [B,S,C]
    float* w2buf = Gbuf + (size_t)nB * nS * nC;            // [B,M,C]

    kern_g<<<nB * NST, 256, 0, stream>>>(ctx, resp, Gbuf);
    kern_b<<<nB * NMT, 256, 0, stream>>>(ctx, pos, mask, Gbuf, w2buf);
    kern_c<<<nB, 256, 0, stream>>>(w2buf, out);
}

// Round 2
// 186.574 us; speedup vs baseline: 5.1159x; 5.1159x over previous
//
#include <hip/hip_runtime.h>

using bf16x8 = __attribute__((ext_vector_type(8))) short;
using f32x4  = __attribute__((ext_vector_type(4))) float;

namespace {
constexpr int nB = 128;
constexpr int nS = 300;
constexpr int nC = 64;
constexpr int nH = 768;
constexpr int nM = 300;
constexpr int SP = 320;                 // padded S (10 k-steps of 32 for PV)
constexpr int MT = 32;                  // m-tile in kern_b
constexpr int NMT = 5;                  // ceil(300/64)... 320/64 -> 5 tiles of 64? no: 10*32=320 -> 5*64.. MT=32 -> 10? see grid
// NOTE: m-tiles of 32 over padded M=320 -> 10 tiles, but we use 5*64? No:
// grid uses NMTILES = SP/MT = 10.
constexpr int NMTILES = SP / MT;        // 10
constexpr int KCB = 32;                 // k-chunk kern_b
constexpr int NKCB = nH / KCB;          // 24
constexpr int KCG = 64;                 // k-chunk kern_g
constexpr int NKCG = nH / KCG;          // 12
}

__device__ __forceinline__ unsigned short bf16rne(float f) {
    unsigned u = __float_as_uint(f);
    return (unsigned short)((u + 0x7FFFu + ((u >> 16) & 1u)) >> 16);
}
__device__ __forceinline__ unsigned pack2(float a, float b) {
    return (unsigned)bf16rne(a) | ((unsigned)bf16rne(b) << 16);
}

// ---------------------------------------------------------------------------
// kern_g: G[b,s,c] = sum_h ctx[b,s,h]*resp[b,c,h], written transposed as
// Gt[b][c][SP] bf16 (s >= nS left unwritten; PV multiplies them by P=0).
// grid 256 = (b, s-half), 256 threads, XCD-swizzled.
// ---------------------------------------------------------------------------
__global__ __launch_bounds__(256, 2) void kern_g(const float* __restrict__ ctx,
                                                 const float* __restrict__ resp,
                                                 unsigned short* __restrict__ Gt) {
    __shared__ char ctxS[160 * 128];   // [160 s][64 k] bf16, 128B rows, XOR swz
    __shared__ char respS[64 * 128];   // [64 c][64 k] bf16

    const int d = blockIdx.x;
    const int x = d & 7, j = d >> 3;
    const int b  = (j >> 1) * 8 + x;
    const int s0 = (j & 1) * 160;
    const int tid = threadIdx.x;
    const int lane = tid & 63, wv = tid >> 6;

    const float* __restrict__ ctxb  = ctx  + (size_t)b * nS * nH;
    const float* __restrict__ respb = resp + (size_t)b * nC * nH;

    f32x4 acc[5][2];
    #pragma unroll
    for (int i = 0; i < 5; ++i)
        #pragma unroll
        for (int t = 0; t < 2; ++t) acc[i][t] = (f32x4){0.f, 0.f, 0.f, 0.f};

    const int sbase = (wv >> 1) * 80;   // wave s-range within 160
    const int cbase = (wv & 1) * 32;    // wave c-range

    for (int kc = 0; kc < NKCG; ++kc) {
        const int k0 = kc * KCG;
        __syncthreads();
        #pragma unroll
        for (int i = 0; i < 10; ++i) {           // ctx: 160*16 quads
            int q = i * 256 + tid;
            int r = q >> 4, kq = q & 15;
            int s = s0 + r; s = (s < nS) ? s : (nS - 1);
            float4 v = *(const float4*)(ctxb + (size_t)s * nH + k0 + kq * 4);
            int byte = r * 128 + ((kq * 8) ^ ((r & 7) << 4));
            *(uint2*)(ctxS + byte) = make_uint2(pack2(v.x, v.y), pack2(v.z, v.w));
        }
        #pragma unroll
        for (int i = 0; i < 4; ++i) {            // resp: 64*16 quads
            int q = i * 256 + tid;
            int r = q >> 4, kq = q & 15;
            float4 v = *(const float4*)(respb + (size_t)r * nH + k0 + kq * 4);
            int byte = r * 128 + ((kq * 8) ^ ((r & 7) << 4));
            *(uint2*)(respS + byte) = make_uint2(pack2(v.x, v.y), pack2(v.z, v.w));
        }
        __syncthreads();
        #pragma unroll
        for (int ks = 0; ks < 2; ++ks) {
            const int kb = (ks * 32 + (lane >> 4) * 8) * 2;   // byte k-offset
            bf16x8 a[5], bb[2];
            #pragma unroll
            for (int sj = 0; sj < 5; ++sj) {
                int r = sbase + sj * 16 + (lane & 15);
                a[sj] = *(const bf16x8*)(ctxS + r * 128 + (kb ^ ((r & 7) << 4)));
            }
            #pragma unroll
            for (int t = 0; t < 2; ++t) {
                int c = cbase + t * 16 + (lane & 15);
                bb[t] = *(const bf16x8*)(respS + c * 128 + (kb ^ ((c & 7) << 4)));
            }
            #pragma unroll
            for (int sj = 0; sj < 5; ++sj)
                #pragma unroll
                for (int t = 0; t < 2; ++t)
                    acc[sj][t] = __builtin_amdgcn_mfma_f32_16x16x32_bf16(
                        a[sj], bb[t], acc[sj][t], 0, 0, 0);
        }
    }
    // write Gt[b][c][s]: C layout col=lane&15 (=c), row=(lane>>4)*4+r (=s)
    unsigned short* gdst = Gt + (size_t)b * nC * SP;
    #pragma unroll
    for (int sj = 0; sj < 5; ++sj) {
        #pragma unroll
        for (int t = 0; t < 2; ++t) {
            int c = cbase + t * 16 + (lane & 15);
            #pragma unroll
            for (int r = 0; r < 4; ++r) {
                int s = s0 + sbase + sj * 16 + (lane >> 4) * 4 + r;
                if (s < nS) gdst[c * SP + s] = bf16rne(acc[sj][t][r]);
            }
        }
    }
}

// ---------------------------------------------------------------------------
// kern_b: per (b, m-tile of 32):
//  logits W[m,s]=pos[m]·ctx[b,s] via MFMA (bf16), masked -> softmax ->
//  P bf16 (1/sum folded) -> w2 = P·G via MFMA -> sum_m w2^2 -> atomicAdd out.
// grid 640 = 128 b * 5?? -> actually 128 * (SP/MT=10)/2... grid = nB*NMTILES/?? 
// grid = nB * NMTILES? M padded 320/32 = 10 tiles -> but only ceil(300/32)=10.
// grid = 1280, XCD-swizzled so same-b blocks share an XCD.
// ---------------------------------------------------------------------------
__global__ __launch_bounds__(256, 2) void kern_b(const float* __restrict__ ctx,
                                                 const float* __restrict__ pos,
                                                 const int*  __restrict__ mask,
                                                 const unsigned short* __restrict__ Gt,
                                                 float* __restrict__ out) {
    // region A (41,984 B): phase1 staging (ctx 20,480 + pos 2,048) | Wrow | GtS
    __shared__ __align__(16) char regA[32 * 328 * 4];
    __shared__ __align__(16) char PbS[32 * 640];     // P bf16 [32][320], swz
    __shared__ float maskS[SP];
    __shared__ float rowSc[MT];

    char* ctxS = regA;                    // [320 s][32 k] bf16, 64B rows
    char* posS = regA + 320 * 64;         // [32 m][32 k] bf16, 64B rows
    float* Wrow = (float*)regA;           // [32][328] f32
    char* GtS = regA;                     // [64 c][320 s] bf16, 640B rows

    const int d = blockIdx.x;
    const int x = d & 7, jj = d >> 3;     // jj in [0,160)
    const int b  = (jj / NMTILES) * 8 + x;
    const int m0 = (jj % NMTILES) * MT;
    const int tid = threadIdx.x;
    const int lane = tid & 63, wv = tid >> 6;

    for (int s = tid; s < SP; s += 256)
        maskS[s] = (s < nS) ? (float)mask[b * nS + s] : 0.f;

    const float* __restrict__ ctxb = ctx + (size_t)b * nS * nH;

    f32x4 acc[2][5];
    #pragma unroll
    for (int f = 0; f < 2; ++f)
        #pragma unroll
        for (int sj = 0; sj < 5; ++sj) acc[f][sj] = (f32x4){0.f, 0.f, 0.f, 0.f};

    const int wbase = wv * 80;            // wave s-range

    // ---- phase 1: logits via MFMA, K-chunks of 32 ----
    for (int kc = 0; kc < NKCB; ++kc) {
        const int k0 = kc * KCB;
        __syncthreads();
        #pragma unroll
        for (int i = 0; i < 10; ++i) {            // ctx: 320 rows * 8 quads
            int q = i * 256 + tid;
            int r = q >> 3, kq = q & 7;
            int s = (r < nS) ? r : (nS - 1);
            float4 v = *(const float4*)(ctxb + (size_t)s * nH + k0 + kq * 4);
            int byte = r * 64 + ((kq * 8) ^ (((r >> 1) & 3) << 4));
            *(uint2*)(ctxS + byte) = make_uint2(pack2(v.x, v.y), pack2(v.z, v.w));
        }
        {                                          // pos: 32 rows * 8 quads
            int r = tid >> 3, kq = tid & 7;
            int m = m0 + r; m = (m < nM) ? m : (nM - 1);
            float4 v = *(const float4*)(pos + (size_t)m * nH + k0 + kq * 4);
            int byte = r * 64 + ((kq * 8) ^ (((r >> 1) & 3) << 4));
            *(uint2*)(posS + byte) = make_uint2(pack2(v.x, v.y), pack2(v.z, v.w));
        }
        __syncthreads();
        const int kb = ((lane >> 4) * 8) * 2;      // 0,16,32,48
        bf16x8 a[2], bs[5];
        #pragma unroll
        for (int f = 0; f < 2; ++f) {
            int m = f * 16 + (lane & 15);
            a[f] = *(const bf16x8*)(posS + m * 64 + (kb ^ (((m >> 1) & 3) << 4)));
        }
        #pragma unroll
        for (int sj = 0; sj < 5; ++sj) {
            int s = wbase + sj * 16 + (lane & 15);
            bs[sj] = *(const bf16x8*)(ctxS + s * 64 + (kb ^ (((s >> 1) & 3) << 4)));
        }
        #pragma unroll
        for (int f = 0; f < 2; ++f)
            #pragma unroll
            for (int sj = 0; sj < 5; ++sj)
                acc[f][sj] = __builtin_amdgcn_mfma_f32_16x16x32_bf16(
                    a[f], bs[sj], acc[f][sj], 0, 0, 0);
    }

    // ---- C-write (masked) into Wrow ----
    __syncthreads();   // staging region becomes Wrow
    #pragma unroll
    for (int f = 0; f < 2; ++f) {
        #pragma unroll
        for (int sj = 0; sj < 5; ++sj) {
            int s = wbase + sj * 16 + (lane & 15);
            float mv = (s < nS) ? maskS[s] : 0.f;
            #pragma unroll
            for (int r = 0; r < 4; ++r) {
                int m = f * 16 + (lane >> 4) * 4 + r;
                Wrow[m * 328 + s] = (s < nS) ? acc[f][sj][r] * mv : -1e30f;
            }
        }
    }
    __syncthreads();

    // ---- softmax over s (rows of 32, 8 lanes each) ----
    {
        const int row = tid >> 3, l8 = tid & 7;
        float mx = -1e30f;
        for (int s = l8; s < SP; s += 8) mx = fmaxf(mx, Wrow[row * 328 + s]);
        mx = fmaxf(mx, __shfl_xor(mx, 1));
        mx = fmaxf(mx, __shfl_xor(mx, 2));
        mx = fmaxf(mx, __shfl_xor(mx, 4));
        float sum = 0.f;
        for (int s = l8; s < SP; s += 8) {
            float e = __expf(Wrow[row * 328 + s] - mx);
            Wrow[row * 328 + s] = e;
            sum += e;
        }
        sum += __shfl_xor(sum, 1);
        sum += __shfl_xor(sum, 2);
        sum += __shfl_xor(sum, 4);
        if (l8 == 0) rowSc[row] = 1.f / sum;
    }
    __syncthreads();

    // ---- P = e * rowScale, bf16, swizzled [32][320] (zero for pad rows/cols) ----
    #pragma unroll
    for (int i = 0; i < 10; ++i) {
        int q = i * 256 + tid;                 // 32 rows * 80 quads
        int m = q / 80, sq = q % 80;
        float scl = ((m0 + m) < nM && sq < 75) ? rowSc[m] : 0.f;
        float4 e = *(const float4*)(Wrow + m * 328 + sq * 4);
        int byte = m * 640 + ((sq * 8) ^ ((m & 7) << 4));
        *(uint2*)(PbS + byte) =
            make_uint2(pack2(e.x * scl, e.y * scl), pack2(e.z * scl, e.w * scl));
    }
    __syncthreads();

    // ---- stage Gt[b] (Wrow region dead) ----
    {
        const unsigned short* gsrc = Gt + (size_t)b * nC * SP;
        #pragma unroll
        for (int i = 0; i < 10; ++i) {
            int slot = i * 256 + tid;          // 2560 x 16B
            int r = slot / 40, cw = slot % 40;
            int4 v = *(const int4*)(gsrc + r * SP + cw * 8);
            int byte = r * 640 + ((cw * 16) ^ ((r & 7) << 4));
            *(int4*)(GtS + byte) = v;
        }
    }
    __syncthreads();

    // ---- PV: w2[m,c] = sum_s P[m,s]*G[s,c]; then sum_m w2^2 -> atomic ----
    f32x4 pacc[2];
    #pragma unroll
    for (int t = 0; t < 2; ++t) pacc[t] = (f32x4){0.f, 0.f, 0.f, 0.f};
    const int mf = (wv >> 1);                  // wave's m-frag (0/1)
    const int cf = (wv & 1) * 2;               // wave's first c-frag
    #pragma unroll
    for (int ks = 0; ks < 10; ++ks) {
        const int kb = (ks * 32 + (lane >> 4) * 8) * 2;
        int m = mf * 16 + (lane & 15);
        bf16x8 a = *(const bf16x8*)(PbS + m * 640 + (kb ^ ((m & 7) << 4)));
        #pragma unroll
        for (int tt = 0; tt < 2; ++tt) {
            int c = (cf + tt) * 16 + (lane & 15);
            bf16x8 g = *(const bf16x8*)(GtS + c * 640 + (kb ^ ((c & 7) << 4)));
            pacc[tt] = __builtin_amdgcn_mfma_f32_16x16x32_bf16(a, g, pacc[tt], 0, 0, 0);
        }
    }
    #pragma unroll
    for (int tt = 0; tt < 2; ++tt) {
        float v = 0.f;
        #pragma unroll
        for (int r = 0; r < 4; ++r) v += pacc[tt][r] * pacc[tt][r];
        v += __shfl_xor(v, 16);
        v += __shfl_xor(v, 32);
        if (lane < 16) atomicAdd(out + b * nC + (cf + tt) * 16 + lane, v);
    }
}

extern "C" void kernel_launch(void* const* d_in, const int* in_sizes, int n_in,
                              void* d_out, int out_size, void* d_ws, size_t ws_size,
                              hipStream_t stream) {
    const float* ctx  = (const float*)d_in[0];   // [B,S,H]
    const float* resp = (const float*)d_in[1];   // [B,C,H]
    const float* pos  = (const float*)d_in[2];   // [M,H]
    const int*   mask = (const int*)d_in[3];     // [B,S]
    float* out = (float*)d_out;                  // [B,C]

    unsigned short* Gt = (unsigned short*)d_ws;  // [B][C][SP] bf16 = 5.24 MB

    hipMemsetAsync(d_out, 0, (size_t)nB * nC * sizeof(float), stream);
    kern_g<<<256, 256, 0, stream>>>(ctx, resp, Gt);
    kern_b<<<nB * NMTILES, 256, 0, stream>>>(ctx, pos, mask, Gt, out);
}

// Round 3
// 71.643 us; speedup vs baseline: 13.3228x; 2.6042x over previous
//
#include <hip/hip_runtime.h>

using bf16x8 = __attribute__((ext_vector_type(8))) short;
using bf16x4 = __attribute__((ext_vector_type(4))) short;
using f32x4  = __attribute__((ext_vector_type(4))) float;

namespace {
constexpr int nB = 128, nS = 300, nC = 64, nH = 768, nM = 300;
constexpr int MT  = 160;            // m-tile per block (2 blocks per b)
constexpr int KC  = 32;             // k chunk
constexpr int NKC = nH / KC;        // 24
// LDS offsets (bytes). Staging (single-buffer) lives at [0,34816) during the
// K-loop; W2RED overlays it after PV. GTS / RED are disjoint regions.
constexpr int STG_CTX  = 0;         // [320 s][64 B]  bf16 k-chunk
constexpr int STG_POS  = 20480;     // [160 m][64 B]
constexpr int STG_RESP = 30720;     // [64 c][64 B]   -> staging ends 34816
constexpr int W2RED    = 0;         // [160][68] f32 = 43520 (post-PV only)
constexpr int GTS      = 43520;     // [64 c][640 B]  bf16 = 40960 -> 84480
constexpr int RED      = 84480;     // 4*160*4 = 2560 -> 87040 (also FRED 8*64*4)
constexpr int LDSB     = 87040;
}

__device__ __forceinline__ unsigned short bf16rne(float f) {
    unsigned u = __float_as_uint(f);
    return (unsigned short)((u + 0x7FFFu + ((u >> 16) & 1u)) >> 16);
}
__device__ __forceinline__ unsigned pack2(float a, float b) {
    return (unsigned)bf16rne(a) | ((unsigned)bf16rne(b) << 16);
}

__device__ __forceinline__ f32x4 mfma16(bf16x4 a, bf16x4 b, f32x4 c) {
#if __has_builtin(__builtin_amdgcn_mfma_f32_16x16x16bf16_1k)
    return __builtin_amdgcn_mfma_f32_16x16x16bf16_1k(a, b, c, 0, 0, 0);
#else
    asm volatile("v_mfma_f32_16x16x16_bf16 %0, %1, %2, %0"
                 : "+v"(c) : "v"(a), "v"(b));
    return c;
#endif
}

// ---------------------------------------------------------------------------
// One block per (b, m-half). 512 threads = 8 waves: wave = (sg in 0..3, mg in 0..1).
// Phase 1 (K-loop): stage ctx/pos/resp chunk (fp32->bf16) once; MFMA both
//   logits (swapped: D[s][m]) and G (D[s][c]).
// Phase 2: GtS write, in-register masked softmax (cross-wave via RED).
// Phase 3: PV via 16x16x16 MFMA with in-register P A-frags; w2 cross-wave
//   reduce (ordered passes); square-sum; one atomicAdd per (block, c).
// ---------------------------------------------------------------------------
__global__ __launch_bounds__(512, 2) void fused(const float* __restrict__ ctx,
                                                const float* __restrict__ resp,
                                                const float* __restrict__ pos,
                                                const int*  __restrict__ mask,
                                                float* __restrict__ out) {
    extern __shared__ char sm[];
    const int b   = blockIdx.x & 127;
    const int mh  = blockIdx.x >> 7;
    const int m0  = mh * MT;
    const int tid = threadIdx.x;
    const int ln  = tid & 63, wv = tid >> 6;
    const int l15 = ln & 15, g = ln >> 4;
    const int sg  = wv & 3, mg = wv >> 2;

    const float* __restrict__ ctxb  = ctx  + (size_t)b * nS * nH;
    const float* __restrict__ respb = resp + (size_t)b * nC * nH;

    f32x4 acc[5][5];    // logits: D[s(sj)][m(mj)] swapped
    f32x4 gacc[5][2];   // G: D[s(sj)][c(cj within mg pair)]
    #pragma unroll
    for (int i = 0; i < 5; ++i) {
        #pragma unroll
        for (int j = 0; j < 5; ++j) acc[i][j] = (f32x4){0.f, 0.f, 0.f, 0.f};
        gacc[i][0] = (f32x4){0.f, 0.f, 0.f, 0.f};
        gacc[i][1] = (f32x4){0.f, 0.f, 0.f, 0.f};
    }

    float4 cR[5], pR[3], rR;
    auto loads = [&](int t) {
        const int k0 = t * KC;
        #pragma unroll
        for (int i = 0; i < 5; ++i) {
            int q = i * 512 + tid, r = q >> 3, kq = q & 7;
            int s = (r < nS) ? r : (nS - 1);
            cR[i] = *(const float4*)(ctxb + (size_t)s * nH + k0 + kq * 4);
        }
        #pragma unroll
        for (int i = 0; i < 3; ++i) {
            int q = i * 512 + tid;
            if (q < 1280) {
                int r = q >> 3, kq = q & 7;
                int m = m0 + r; if (m >= nM) m = nM - 1;
                pR[i] = *(const float4*)(pos + (size_t)m * nH + k0 + kq * 4);
            }
        }
        { int r = tid >> 3, kq = tid & 7;
          rR = *(const float4*)(respb + (size_t)r * nH + k0 + kq * 4); }
    };

    loads(0);
    for (int t = 0; t < NKC; ++t) {
        __syncthreads();   // previous chunk's MFMA frag-reads done
        #pragma unroll
        for (int i = 0; i < 5; ++i) {
            int q = i * 512 + tid, r = q >> 3, kq = q & 7;
            *(uint2*)(sm + STG_CTX + r * 64 + kq * 8) =
                make_uint2(pack2(cR[i].x, cR[i].y), pack2(cR[i].z, cR[i].w));
        }
        #pragma unroll
        for (int i = 0; i < 3; ++i) {
            int q = i * 512 + tid;
            if (q < 1280) {
                int r = q >> 3, kq = q & 7;
                *(uint2*)(sm + STG_POS + r * 64 + kq * 8) =
                    make_uint2(pack2(pR[i].x, pR[i].y), pack2(pR[i].z, pR[i].w));
            }
        }
        { int r = tid >> 3, kq = tid & 7;
          *(uint2*)(sm + STG_RESP + r * 64 + kq * 8) =
              make_uint2(pack2(rR.x, rR.y), pack2(rR.z, rR.w)); }
        if (t + 1 < NKC) loads(t + 1);   // prefetch overlaps MFMA below
        __syncthreads();

        bf16x8 fp[5], fr[2];
        #pragma unroll
        for (int mj = 0; mj < 5; ++mj)
            fp[mj] = *(const bf16x8*)(sm + STG_POS + (80 * mg + 16 * mj + l15) * 64 + g * 16);
        #pragma unroll
        for (int cj = 0; cj < 2; ++cj)
            fr[cj] = *(const bf16x8*)(sm + STG_RESP + (16 * (2 * mg + cj) + l15) * 64 + g * 16);
        #pragma unroll
        for (int sj = 0; sj < 5; ++sj) {
            bf16x8 fa = *(const bf16x8*)(sm + STG_CTX + (80 * sg + 16 * sj + l15) * 64 + g * 16);
            #pragma unroll
            for (int mj = 0; mj < 5; ++mj)
                acc[sj][mj] = __builtin_amdgcn_mfma_f32_16x16x32_bf16(fa, fp[mj], acc[sj][mj], 0, 0, 0);
            #pragma unroll
            for (int cj = 0; cj < 2; ++cj)
                gacc[sj][cj] = __builtin_amdgcn_mfma_f32_16x16x32_bf16(fa, fr[cj], gacc[sj][cj], 0, 0, 0);
        }
    }

    // ---- GtS[c][s] bf16, XOR-swizzled (rows are 640B = bank-aligned) ----
    #pragma unroll
    for (int sj = 0; sj < 5; ++sj)
        #pragma unroll
        for (int cj = 0; cj < 2; ++cj) {
            int c = 16 * (2 * mg + cj) + l15;
            int s = 80 * sg + 16 * sj + 4 * g;
            *(uint2*)(sm + GTS + c * 640 + ((2 * s) ^ ((c & 7) << 3))) =
                make_uint2(pack2(gacc[sj][cj][0], gacc[sj][cj][1]),
                           pack2(gacc[sj][cj][2], gacc[sj][cj][3]));
        }

    // ---- mask apply (multiplicative mask, s>=300 excluded) ----
    #pragma unroll
    for (int sj = 0; sj < 5; ++sj)
        #pragma unroll
        for (int r = 0; r < 4; ++r) {
            int s = 80 * sg + 16 * sj + 4 * g + r;
            if (s < nS) {
                float mv = (float)mask[b * nS + s];
                #pragma unroll
                for (int mj = 0; mj < 5; ++mj) acc[sj][mj][r] *= mv;
            } else {
                #pragma unroll
                for (int mj = 0; mj < 5; ++mj) acc[sj][mj][r] = -1e30f;
            }
        }

    // ---- softmax over s: in-reg 20-reduce + shfl over lane-groups + LDS over 4 s-waves ----
    float* red = (float*)(sm + RED);
    float inv[5];
    {
        float mx[5];
        #pragma unroll
        for (int mj = 0; mj < 5; ++mj) {
            float m = -1e30f;
            #pragma unroll
            for (int sj = 0; sj < 5; ++sj)
                #pragma unroll
                for (int r = 0; r < 4; ++r) m = fmaxf(m, acc[sj][mj][r]);
            m = fmaxf(m, __shfl_xor(m, 16));
            m = fmaxf(m, __shfl_xor(m, 32));
            mx[mj] = m;
        }
        if (ln < 16) {
            #pragma unroll
            for (int mj = 0; mj < 5; ++mj) red[sg * 160 + 80 * mg + 16 * mj + ln] = mx[mj];
        }
        __syncthreads();
        float m4[5];
        #pragma unroll
        for (int mj = 0; mj < 5; ++mj) {
            int idx = 80 * mg + 16 * mj + l15;
            m4[mj] = fmaxf(fmaxf(red[idx], red[160 + idx]),
                           fmaxf(red[320 + idx], red[480 + idx]));
        }
        __syncthreads();
        float sum[5];
        #pragma unroll
        for (int mj = 0; mj < 5; ++mj) {
            float s = 0.f;
            #pragma unroll
            for (int sj = 0; sj < 5; ++sj)
                #pragma unroll
                for (int r = 0; r < 4; ++r) {
                    float e = __expf(acc[sj][mj][r] - m4[mj]);
                    acc[sj][mj][r] = e;
                    s += e;
                }
            s += __shfl_xor(s, 16);
            s += __shfl_xor(s, 32);
            sum[mj] = s;
        }
        if (ln < 16) {
            #pragma unroll
            for (int mj = 0; mj < 5; ++mj) red[sg * 160 + 80 * mg + 16 * mj + ln] = sum[mj];
        }
        __syncthreads();
        #pragma unroll
        for (int mj = 0; mj < 5; ++mj) {
            int idx = 80 * mg + 16 * mj + l15;
            float tt = red[idx] + red[160 + idx] + red[320 + idx] + red[480 + idx];
            int mglob = m0 + 80 * mg + 16 * mj + l15;
            inv[mj] = (mglob < nM) ? (1.0f / tt) : 0.0f;   // pad m rows -> P = 0
        }
    }

    // ---- P fragments in-register (A-layout of 16x16x16: k = 4*g + j matches) ----
    bf16x4 P[5][5];
    #pragma unroll
    for (int sj = 0; sj < 5; ++sj)
        #pragma unroll
        for (int mj = 0; mj < 5; ++mj) {
            uint2 u = make_uint2(pack2(acc[sj][mj][0] * inv[mj], acc[sj][mj][1] * inv[mj]),
                                 pack2(acc[sj][mj][2] * inv[mj], acc[sj][mj][3] * inv[mj]));
            P[sj][mj] = __builtin_bit_cast(bf16x4, u);
        }

    // ---- PV: partial w2 over this wave's s-range (GtS writes fenced by softmax barriers) ----
    f32x4 pacc[5][4];
    #pragma unroll
    for (int mj = 0; mj < 5; ++mj)
        #pragma unroll
        for (int cj = 0; cj < 4; ++cj) pacc[mj][cj] = (f32x4){0.f, 0.f, 0.f, 0.f};
    #pragma unroll
    for (int sj = 0; sj < 5; ++sj) {
        int s = 80 * sg + 16 * sj + 4 * g;
        #pragma unroll
        for (int cj = 0; cj < 4; ++cj) {
            int c = 16 * cj + l15;
            bf16x4 B = *(const bf16x4*)(sm + GTS + c * 640 + ((2 * s) ^ ((c & 7) << 3)));
            #pragma unroll
            for (int mj = 0; mj < 5; ++mj) pacc[mj][cj] = mfma16(P[sj][mj], B, pacc[mj][cj]);
        }
    }
    __syncthreads();

    // ---- ordered cross-wave w2 reduce (deterministic) ----
    float* w2r = (float*)(sm + W2RED);   // [160][68] f32, overlays dead staging
    for (int pass = 0; pass < 4; ++pass) {
        if (sg == pass) {
            #pragma unroll
            for (int mj = 0; mj < 5; ++mj)
                #pragma unroll
                for (int cj = 0; cj < 4; ++cj)
                    #pragma unroll
                    for (int r = 0; r < 4; ++r) {
                        int m = 80 * mg + 16 * mj + 4 * g + r;
                        int idx = m * 68 + 16 * cj + l15;
                        if (pass == 0) w2r[idx] = pacc[mj][cj][r];
                        else           w2r[idx] += pacc[mj][cj][r];
                    }
        }
        __syncthreads();
    }

    // ---- dot partial = sum_m w2^2 ; one atomic per (block, c) -> 2 per out elem ----
    float* fred = (float*)(sm + RED);
    {
        int c = tid & 63, g8 = tid >> 6;
        float s = 0.f;
        #pragma unroll 4
        for (int i = 0; i < 20; ++i) {
            float v = w2r[(g8 + 8 * i) * 68 + c];
            s += v * v;
        }
        fred[g8 * 64 + c] = s;
    }
    __syncthreads();
    if (tid < 64) {
        float t = 0.f;
        #pragma unroll
        for (int j = 0; j < 8; ++j) t += fred[j * 64 + tid];
        atomicAdd(out + b * nC + tid, t);
    }
}

extern "C" void kernel_launch(void* const* d_in, const int* in_sizes, int n_in,
                              void* d_out, int out_size, void* d_ws, size_t ws_size,
                              hipStream_t stream) {
    const float* ctx  = (const float*)d_in[0];   // [B,S,H]
    const float* resp = (const float*)d_in[1];   // [B,C,H]
    const float* pos  = (const float*)d_in[2];   // [M,H]
    const int*   mask = (const int*)d_in[3];     // [B,S]
    float* out = (float*)d_out;                  // [B,C]

    hipFuncSetAttribute((const void*)fused,
                        hipFuncAttributeMaxDynamicSharedMemorySize, LDSB);
    hipMemsetAsync(d_out, 0, (size_t)nB * nC * sizeof(float), stream);
    fused<<<nB * 2, 512, LDSB, stream>>>(ctx, resp, pos, mask, out);
}

// Round 5
// 52.917 us; speedup vs baseline: 18.0374x; 1.3539x over previous
//
#include <hip/hip_runtime.h>

using bf16x8 = __attribute__((ext_vector_type(8))) short;
using bf16x4 = __attribute__((ext_vector_type(4))) short;
using f32x4  = __attribute__((ext_vector_type(4))) float;

namespace {
constexpr int nB = 128, nS = 300, nC = 64, nH = 768, nM = 300;
constexpr int MT  = 160;            // m-tile per block (2 blocks per b)
constexpr int KC  = 32;             // k chunk
constexpr int NKC = nH / KC;        // 24
// LDS (bytes): two staging buffers [0,69632); GTS overlays buf1 tail after the
// K-loop; W2RED overlays buf0 after PV; RED is disjoint.
constexpr int BUFSZ    = 34816;     // ctx 20480 + pos 10240 + resp 4096
constexpr int STG_CTX  = 0;         // [320 s][64 B] bf16 chunk, XOR-swizzled
constexpr int STG_POS  = 20480;     // [160 m][64 B]
constexpr int STG_RESP = 30720;     // [64 c][64 B]
constexpr int GTS      = 43520;     // [64 c][640 B] bf16 -> ends 84480
constexpr int W2RED    = 0;         // [64 c][164 f32] = 41984 (post-PV only)
constexpr int RED      = 84480;     // 2560 B (softmax red / final red)
constexpr int LDSB     = 87040;
}

__device__ __forceinline__ unsigned short bf16rne(float f) {
    unsigned u = __float_as_uint(f);
    return (unsigned short)((u + 0x7FFFu + ((u >> 16) & 1u)) >> 16);
}
__device__ __forceinline__ unsigned pack2(float a, float b) {
    return (unsigned)bf16rne(a) | ((unsigned)bf16rne(b) << 16);
}
__device__ __forceinline__ uint2 cvt4(float4 v) {
    return make_uint2(pack2(v.x, v.y), pack2(v.z, v.w));
}
// staging swizzle: XOR row bits into byte-cols 16..48 (keeps 8B/16B contiguity)
__device__ __forceinline__ int swz(int row, int bcol) {
    return row * 64 + (bcol ^ ((row & 3) << 4));
}

__device__ __forceinline__ f32x4 mfma16(bf16x4 a, bf16x4 b, f32x4 c) {
#if __has_builtin(__builtin_amdgcn_mfma_f32_16x16x16bf16_1k)
    return __builtin_amdgcn_mfma_f32_16x16x16bf16_1k(a, b, c, 0, 0, 0);
#else
    asm volatile("v_mfma_f32_16x16x16_bf16 %0, %1, %2, %0"
                 : "+v"(c) : "v"(a), "v"(b));
    return c;
#endif
}

// ---------------------------------------------------------------------------
// One block per (b, m-half). 512 threads = 8 waves: wave = (sg 0..3, mg 0..1).
// K-loop: double-buffered reg-staged fp32->bf16 chunks; per chunk ONE barrier;
//   MFMA both logits (swapped D[s][m]) and G (D[s][c]) from the same ctx tile.
// Then: GtS write, in-register masked softmax, PV with in-register P A-frags,
//   ordered cross-wave w2 reduce (float4), square-sum, 1 atomic per (block,c).
// ---------------------------------------------------------------------------
__global__ __launch_bounds__(512, 2) void fused(const float* __restrict__ ctx,
                                                const float* __restrict__ resp,
                                                const float* __restrict__ pos,
                                                const int*  __restrict__ mask,
                                                float* __restrict__ out) {
    extern __shared__ char sm[];
    const int b   = blockIdx.x & 127;
    const int mh  = blockIdx.x >> 7;
    const int m0  = mh * MT;
    const int tid = threadIdx.x;
    const int ln  = tid & 63, wv = tid >> 6;
    const int l15 = ln & 15, g = ln >> 4;
    const int sg  = wv & 3, mg = wv >> 2;

    const float* __restrict__ ctxb  = ctx  + (size_t)b * nS * nH;
    const float* __restrict__ respb = resp + (size_t)b * nC * nH;

    f32x4 acc[5][5];    // logits: D[s(sj)][m(mj)] swapped
    f32x4 gacc[5][2];   // G: D[s(sj)][c(cj within mg pair)]
    #pragma unroll
    for (int i = 0; i < 5; ++i) {
        #pragma unroll
        for (int j = 0; j < 5; ++j) acc[i][j] = (f32x4){0.f, 0.f, 0.f, 0.f};
        gacc[i][0] = (f32x4){0.f, 0.f, 0.f, 0.f};
        gacc[i][1] = (f32x4){0.f, 0.f, 0.f, 0.f};
    }

    float4 cR[5], pR[3], rR;
    auto loads = [&](int t) {
        const int k0 = t * KC;
        #pragma unroll
        for (int i = 0; i < 5; ++i) {
            int q = i * 512 + tid, r = q >> 3, kq = q & 7;
            int s = (r < nS) ? r : (nS - 1);
            cR[i] = *(const float4*)(ctxb + (size_t)s * nH + k0 + kq * 4);
        }
        #pragma unroll
        for (int i = 0; i < 3; ++i) {
            int q = i * 512 + tid;
            if (q < 1280) {
                int r = q >> 3, kq = q & 7;
                int m = m0 + r; if (m >= nM) m = nM - 1;
                pR[i] = *(const float4*)(pos + (size_t)m * nH + k0 + kq * 4);
            }
        }
        { int r = tid >> 3, kq = tid & 7;
          rR = *(const float4*)(respb + (size_t)r * nH + k0 + kq * 4); }
    };
    auto stage = [&](char* base) {
        #pragma unroll
        for (int i = 0; i < 5; ++i) {
            int q = i * 512 + tid, r = q >> 3, kq = q & 7;
            *(uint2*)(base + STG_CTX + swz(r, kq * 8)) = cvt4(cR[i]);
        }
        #pragma unroll
        for (int i = 0; i < 3; ++i) {
            int q = i * 512 + tid;
            if (q < 1280) {
                int r = q >> 3, kq = q & 7;
                *(uint2*)(base + STG_POS + swz(r, kq * 8)) = cvt4(pR[i]);
            }
        }
        { int r = tid >> 3, kq = tid & 7;
          *(uint2*)(base + STG_RESP + swz(r, kq * 8)) = cvt4(rR); }
    };

    // prologue: fill buf0 (chunk 0), load chunk 1 into regs
    loads(0);
    stage(sm);
    loads(1);
    __syncthreads();

    int cur = 0;
    for (int t = 0; t < NKC; ++t) {
        char* rbase = sm + cur * BUFSZ;
        if (t + 1 < NKC) stage(sm + (cur ^ 1) * BUFSZ);  // write next chunk
        if (t + 2 < NKC) loads(t + 2);                   // prefetch t+2
        bf16x8 fp[5], fr[2];
        #pragma unroll
        for (int mj = 0; mj < 5; ++mj) {
            int r = 80 * mg + 16 * mj + l15;
            fp[mj] = *(const bf16x8*)(rbase + STG_POS + swz(r, g * 16));
        }
        #pragma unroll
        for (int cj = 0; cj < 2; ++cj) {
            int r = 16 * (2 * mg + cj) + l15;
            fr[cj] = *(const bf16x8*)(rbase + STG_RESP + swz(r, g * 16));
        }
        #pragma unroll
        for (int sj = 0; sj < 5; ++sj) {
            int r = 80 * sg + 16 * sj + l15;
            bf16x8 fa = *(const bf16x8*)(rbase + STG_CTX + swz(r, g * 16));
            #pragma unroll
            for (int mj = 0; mj < 5; ++mj)
                acc[sj][mj] = __builtin_amdgcn_mfma_f32_16x16x32_bf16(fa, fp[mj], acc[sj][mj], 0, 0, 0);
            #pragma unroll
            for (int cj = 0; cj < 2; ++cj)
                gacc[sj][cj] = __builtin_amdgcn_mfma_f32_16x16x32_bf16(fa, fr[cj], gacc[sj][cj], 0, 0, 0);
        }
        __syncthreads();   // covers: reads of buf[cur] done; writes of buf[cur^1] visible
        cur ^= 1;
    }

    // ---- GtS[c][s] bf16, swizzled (staging dead; GTS overlays buf1 tail) ----
    #pragma unroll
    for (int sj = 0; sj < 5; ++sj)
        #pragma unroll
        for (int cj = 0; cj < 2; ++cj) {
            int c = 16 * (2 * mg + cj) + l15;
            int s = 80 * sg + 16 * sj + 4 * g;
            *(uint2*)(sm + GTS + c * 640 + ((2 * s) ^ ((c & 7) << 3))) =
                make_uint2(pack2(gacc[sj][cj][0], gacc[sj][cj][1]),
                           pack2(gacc[sj][cj][2], gacc[sj][cj][3]));
        }

    // ---- multiplicative mask; pad s rows -> -inf ----
    #pragma unroll
    for (int sj = 0; sj < 5; ++sj)
        #pragma unroll
        for (int r = 0; r < 4; ++r) {
            int s = 80 * sg + 16 * sj + 4 * g + r;
            if (s < nS) {
                float mv = (float)mask[b * nS + s];
                #pragma unroll
                for (int mj = 0; mj < 5; ++mj) acc[sj][mj][r] *= mv;
            } else {
                #pragma unroll
                for (int mj = 0; mj < 5; ++mj) acc[sj][mj][r] = -1e30f;
            }
        }

    // ---- softmax over s: in-reg 20-reduce + shfl + LDS across 4 s-waves ----
    float* red = (float*)(sm + RED);
    float inv[5];
    {
        float mx[5];
        #pragma unroll
        for (int mj = 0; mj < 5; ++mj) {
            float m = -1e30f;
            #pragma unroll
            for (int sj = 0; sj < 5; ++sj)
                #pragma unroll
                for (int r = 0; r < 4; ++r) m = fmaxf(m, acc[sj][mj][r]);
            m = fmaxf(m, __shfl_xor(m, 16));
            m = fmaxf(m, __shfl_xor(m, 32));
            mx[mj] = m;
        }
        if (ln < 16) {
            #pragma unroll
            for (int mj = 0; mj < 5; ++mj) red[sg * 160 + 80 * mg + 16 * mj + ln] = mx[mj];
        }
        __syncthreads();
        float m4[5];
        #pragma unroll
        for (int mj = 0; mj < 5; ++mj) {
            int idx = 80 * mg + 16 * mj + l15;
            m4[mj] = fmaxf(fmaxf(red[idx], red[160 + idx]),
                           fmaxf(red[320 + idx], red[480 + idx]));
        }
        __syncthreads();
        float sum[5];
        #pragma unroll
        for (int mj = 0; mj < 5; ++mj) {
            float s = 0.f;
            #pragma unroll
            for (int sj = 0; sj < 5; ++sj)
                #pragma unroll
                for (int r = 0; r < 4; ++r) {
                    float e = __expf(acc[sj][mj][r] - m4[mj]);
                    acc[sj][mj][r] = e;
                    s += e;
                }
            s += __shfl_xor(s, 16);
            s += __shfl_xor(s, 32);
            sum[mj] = s;
        }
        if (ln < 16) {
            #pragma unroll
            for (int mj = 0; mj < 5; ++mj) red[sg * 160 + 80 * mg + 16 * mj + ln] = sum[mj];
        }
        __syncthreads();
        #pragma unroll
        for (int mj = 0; mj < 5; ++mj) {
            int idx = 80 * mg + 16 * mj + l15;
            float tt = red[idx] + red[160 + idx] + red[320 + idx] + red[480 + idx];
            int mglob = m0 + 80 * mg + 16 * mj + l15;
            inv[mj] = (mglob < nM) ? (1.0f / tt) : 0.0f;   // pad m rows -> P = 0
        }
    }

    // ---- P in-register (16x16x16 A-layout: k = 4*g + j matches swapped C) ----
    bf16x4 P[5][5];
    #pragma unroll
    for (int sj = 0; sj < 5; ++sj)
        #pragma unroll
        for (int mj = 0; mj < 5; ++mj) {
            unsigned lo = pack2(acc[sj][mj][0] * inv[mj], acc[sj][mj][1] * inv[mj]);
            unsigned hi = pack2(acc[sj][mj][2] * inv[mj], acc[sj][mj][3] * inv[mj]);
            bf16x4 p;
            p[0] = (short)(lo & 0xFFFF); p[1] = (short)(lo >> 16);
            p[2] = (short)(hi & 0xFFFF); p[3] = (short)(hi >> 16);
            P[sj][mj] = p;
        }

    // ---- PV: partial w2 over this wave's s-range ----
    f32x4 pacc[5][4];
    #pragma unroll
    for (int mj = 0; mj < 5; ++mj)
        #pragma unroll
        for (int cj = 0; cj < 4; ++cj) pacc[mj][cj] = (f32x4){0.f, 0.f, 0.f, 0.f};
    #pragma unroll
    for (int sj = 0; sj < 5; ++sj) {
        int s = 80 * sg + 16 * sj + 4 * g;
        #pragma unroll
        for (int cj = 0; cj < 4; ++cj) {
            int c = 16 * cj + l15;
            bf16x4 B = *(const bf16x4*)(sm + GTS + c * 640 + ((2 * s) ^ ((c & 7) << 3)));
            #pragma unroll
            for (int mj = 0; mj < 5; ++mj) pacc[mj][cj] = mfma16(P[sj][mj], B, pacc[mj][cj]);
        }
    }
    __syncthreads();

    // ---- ordered cross-wave w2 reduce, float4, layout w2r[c][164] ----
    float* w2r = (float*)(sm + W2RED);
    for (int pass = 0; pass < 4; ++pass) {
        if (sg == pass) {
            #pragma unroll
            for (int cj = 0; cj < 4; ++cj) {
                int c = 16 * cj + l15;
                #pragma unroll
                for (int mj = 0; mj < 5; ++mj) {
                    int m = 80 * mg + 16 * mj + 4 * g;
                    float* p = w2r + c * 164 + m;
                    f32x4 v = pacc[mj][cj];
                    if (pass == 0) {
                        *(f32x4*)p = v;
                    } else {
                        f32x4 o = *(const f32x4*)p;
                        o[0] += v[0]; o[1] += v[1]; o[2] += v[2]; o[3] += v[3];
                        *(f32x4*)p = o;
                    }
                }
            }
        }
        __syncthreads();
    }

    // ---- dot partial = sum_m w2^2 ; one atomic per (block, c) ----
    float* fred = (float*)(sm + RED);
    {
        int c = tid & 63, g8 = wv;          // wave g8 handles m in [20*g8, 20*g8+20)
        float s = 0.f;
        #pragma unroll
        for (int j = 0; j < 5; ++j) {
            f32x4 v = *(const f32x4*)(w2r + c * 164 + 20 * g8 + 4 * j);
            s += v[0] * v[0] + v[1] * v[1] + v[2] * v[2] + v[3] * v[3];
        }
        fred[g8 * 64 + c] = s;
    }
    __syncthreads();
    if (tid < 64) {
        float t = 0.f;
        #pragma unroll
        for (int j = 0; j < 8; ++j) t += fred[j * 64 + tid];
        atomicAdd(out + b * nC + tid, t);
    }
}

extern "C" void kernel_launch(void* const* d_in, const int* in_sizes, int n_in,
                              void* d_out, int out_size, void* d_ws, size_t ws_size,
                              hipStream_t stream) {
    const float* ctx  = (const float*)d_in[0];   // [B,S,H]
    const float* resp = (const float*)d_in[1];   // [B,C,H]
    const float* pos  = (const float*)d_in[2];   // [M,H]
    const int*   mask = (const int*)d_in[3];     // [B,S]
    float* out = (float*)d_out;                  // [B,C]

    (void)hipFuncSetAttribute((const void*)fused,
                              hipFuncAttributeMaxDynamicSharedMemorySize, LDSB);
    (void)hipMemsetAsync(d_out, 0, (size_t)nB * nC * sizeof(float), stream);
    fused<<<nB * 2, 512, LDSB, stream>>>(ctx, resp, pos, mask, out);
}